// Round 5
// baseline (9209.823 us; speedup 1.0000x reference)
//
#include <hip/hip_runtime.h>
#include <cmath>

#define HID    1024
#define VOCAB  32000
#define TLEN   128
#define FC_TILES 2000            // 16-col tiles of fc_w
#define G_TILES  192             // 16-col tiles of w_ih / w_hh

typedef __attribute__((ext_vector_type(8))) short bf16x8;
typedef __attribute__((ext_vector_type(4))) float f32x4;

// ---------------- bf16 split helpers ----------------
__device__ __forceinline__ unsigned short bf_hi(float f) {
  unsigned u = __float_as_uint(f);
  return (unsigned short)((u + 0x7fffu + ((u >> 16) & 1u)) >> 16);
}
__device__ __forceinline__ float bf_f(unsigned short h) {
  return __uint_as_float(((unsigned)h) << 16);
}
__device__ __forceinline__ void split2(float f, unsigned short& hi, unsigned short& lo) {
  hi = bf_hi(f);
  lo = bf_hi(f - bf_f(hi));
}
__device__ __forceinline__ void split8(float4 f0, float4 f1, bf16x8& h8, bf16x8& l8) {
  unsigned short h, l;
  split2(f0.x, h, l); h8[0] = (short)h; l8[0] = (short)l;
  split2(f0.y, h, l); h8[1] = (short)h; l8[1] = (short)l;
  split2(f0.z, h, l); h8[2] = (short)h; l8[2] = (short)l;
  split2(f0.w, h, l); h8[3] = (short)h; l8[3] = (short)l;
  split2(f1.x, h, l); h8[4] = (short)h; l8[4] = (short)l;
  split2(f1.y, h, l); h8[5] = (short)h; l8[5] = (short)l;
  split2(f1.z, h, l); h8[6] = (short)h; l8[6] = (short)l;
  split2(f1.w, h, l); h8[7] = (short)h; l8[7] = (short)l;
}
// monotone (value, smallest-index-wins) packing for u64 atomicMax
__device__ __forceinline__ unsigned long long packmax(float v, int idx) {
  unsigned u = __float_as_uint(v);
  unsigned key = (u & 0x80000000u) ? ~u : (u | 0x80000000u);
  return (((unsigned long long)key) << 32) | (unsigned)(~idx);
}

// ================= workspace layout (bytes) =================
#define OFF_FCWP 0ULL            // 2000 * 65536 B
#define OFF_WIHP 131072000ULL    // 192 * 65536
#define OFF_WHHP 143654912ULL
#define OFF_HFA  156237824ULL    // 4m*32k0*2p*64lane*8e * 2B = 262144
#define OFF_H32  156499968ULL    // 64*1024*4
#define OFF_GIB  156762112ULL    // 4*64*3072*4
#define OFF_GHB  159907840ULL    // 64*3072*4
#define OFF_AMAX 160694272ULL    // 64 * 8
#define WS_NEED  160694784ULL

// ---------------- one-time weight split+pack into fragment order ----------------
// dst[tile][k0][p][lane][8] ; tile=16 cols, k0=32 k-elems
__global__ __launch_bounds__(256) void k_pack(const float* __restrict__ src,
                                              unsigned short* __restrict__ dst,
                                              int ntiles) {
  const int idx = blockIdx.x * 256 + threadIdx.x;   // (tile*32+k0)*64+lane
  if (idx >= ntiles * 2048) return;
  const int tile = idx >> 11;
  const int k0 = (idx >> 6) & 31;
  const int lane = idx & 63;
  const int col = tile * 16 + (lane & 15);
  const int kk = k0 * 32 + (lane >> 4) * 8;
  const float* s = src + (size_t)col * HID + kk;
  float4 f0 = *(const float4*)s;
  float4 f1 = *(const float4*)(s + 4);
  bf16x8 h8, l8;
  split8(f0, f1, h8, l8);
  unsigned short* d = dst + ((size_t)(tile * 32 + k0) * 2) * 512 + lane * 8;
  *(bf16x8*)d = h8;
  *(bf16x8*)(d + 512) = l8;
}

// ---------------- one-time h init from encoder output ----------------
__global__ __launch_bounds__(256) void k_init(const float* __restrict__ enc,
                                              float* __restrict__ h32,
                                              unsigned short* __restrict__ hfA) {
  const int r = blockIdx.x;
  const int tid = threadIdx.x;    // 256 = HID/4
  float4 u = ((const float4*)(enc + (size_t)r * HID))[tid];
  ((float4*)(h32 + (size_t)r * HID))[tid] = u;
  const int m = r >> 4, l15 = r & 15;
#pragma unroll
  for (int i = 0; i < 4; i++) {
    const int j = tid * 4 + i;
    unsigned short h, l;
    split2((&u.x)[i], h, l);
    const int k0 = j >> 5, s = (j >> 3) & 3, e = j & 7;
    const int lane = (s << 4) | l15;
    unsigned short* b = hfA + ((size_t)(m * 32 + k0) * 2) * 512 + lane * 8 + e;
    b[0] = h;
    b[512] = l;
  }
}

// ---------------- shared full-K GEMM core (wave: 16 cols x 64 rows) ----------------
__device__ __forceinline__ void gemm16_fullK(
    const unsigned short* __restrict__ Bp,   // packed tile base (32768 shorts)
    const unsigned short* __restrict__ Ap,   // packed hfA base
    int lane, f32x4 acc[4]) {
  const int lo = lane * 8;
  bf16x8 bh = *(const bf16x8*)(Bp + lo);
  bf16x8 bl = *(const bf16x8*)(Bp + 512 + lo);
  bf16x8 ah[4], al[4];
#pragma unroll
  for (int m = 0; m < 4; m++) {
    ah[m] = *(const bf16x8*)(Ap + m * 32768 + lo);
    al[m] = *(const bf16x8*)(Ap + m * 32768 + 512 + lo);
  }
#pragma unroll
  for (int k0 = 0; k0 < 32; k0++) {
    const int kn = (k0 < 31) ? k0 + 1 : 31;
    bf16x8 nbh = *(const bf16x8*)(Bp + kn * 1024 + lo);
    bf16x8 nbl = *(const bf16x8*)(Bp + kn * 1024 + 512 + lo);
    bf16x8 nah[4], nal[4];
#pragma unroll
    for (int m = 0; m < 4; m++) {
      nah[m] = *(const bf16x8*)(Ap + m * 32768 + kn * 1024 + lo);
      nal[m] = *(const bf16x8*)(Ap + m * 32768 + kn * 1024 + 512 + lo);
    }
#pragma unroll
    for (int m = 0; m < 4; m++) {
      acc[m] = __builtin_amdgcn_mfma_f32_16x16x32_bf16(ah[m], bh, acc[m], 0, 0, 0);
      acc[m] = __builtin_amdgcn_mfma_f32_16x16x32_bf16(al[m], bh, acc[m], 0, 0, 0);
      acc[m] = __builtin_amdgcn_mfma_f32_16x16x32_bf16(ah[m], bl, acc[m], 0, 0, 0);
    }
    bh = nbh; bl = nbl;
#pragma unroll
    for (int m = 0; m < 4; m++) { ah[m] = nah[m]; al[m] = nal[m]; }
  }
}

// ---------------- FC (+fused gh) : logits + atomic argmax ----------------
// grid 548 (500 fc + 48 gh) or 500 at last step; 256 thr = 4 waves x 16 cols, full K
__global__ __launch_bounds__(256) void k_fc(
    const unsigned short* __restrict__ fcwp, const unsigned short* __restrict__ whhp,
    const unsigned short* __restrict__ hfA, const float* __restrict__ fc_b,
    float* __restrict__ out, float* __restrict__ ghb,
    unsigned long long* __restrict__ amax, int t) {
  __shared__ unsigned long long lam[4][64];
  const int bid = blockIdx.x;
  const int tid = threadIdx.x;
  const int w = tid >> 6, lane = tid & 63;
  const int l15 = lane & 15, g = lane >> 4;
  f32x4 acc[4] = {};
  if (bid >= 500) {       // fused gh(t+1) = h_new @ w_hh^T
    const int ct = (bid - 500) * 4 + w;
    gemm16_fullK(whhp + (size_t)ct * 32768, hfA, lane, acc);
    const int gcol = ct * 16 + l15;
#pragma unroll
    for (int m = 0; m < 4; m++)
#pragma unroll
      for (int q = 0; q < 4; q++)
        ghb[(size_t)(m * 16 + g * 4 + q) * 3072 + gcol] = acc[m][q];
    return;
  }
  const int ct = bid * 4 + w;
  gemm16_fullK(fcwp + (size_t)ct * 32768, hfA, lane, acc);
  const int gcol = ct * 16 + l15;
  const float bias = fc_b[gcol];
#pragma unroll
  for (int m = 0; m < 4; m++) {
#pragma unroll
    for (int q = 0; q < 4; q++) {
      float v = acc[m][q] + bias;
      const int row = m * 16 + g * 4 + q;
      out[((size_t)row * TLEN + t) * VOCAB + gcol] = v;
      float b = v; int c = gcol;
#pragma unroll
      for (int d = 1; d < 16; d <<= 1) {
        float ov = __shfl_xor(b, d);
        int oc = __shfl_xor(c, d);
        if (ov > b || (ov == b && oc < c)) { b = ov; c = oc; }
      }
      if (l15 == 0) lam[w][row] = packmax(b, c);
    }
  }
  __syncthreads();
  if (tid < 64) {
    unsigned long long mx = lam[0][tid];
#pragma unroll
    for (int ww = 1; ww < 4; ww++)
      if (lam[ww][tid] > mx) mx = lam[ww][tid];
    atomicMax(&amax[tid], mx);
  }
}

// ---------------- gi = x @ w_ih^T with inline token-read + emb gather/split ----------------
// grid 192 = 48 cb x 4 ks ; wave: 16 cols, K-slice 256
__global__ __launch_bounds__(256) void k_gi(
    const float* __restrict__ emb, const unsigned short* __restrict__ wihp,
    const int* __restrict__ tt, const unsigned long long* __restrict__ amax,
    float* __restrict__ gib, int t) {
  const int bid = blockIdx.x;
  const int cb = bid >> 2, ks = bid & 3;
  const int tid = threadIdx.x;
  const int w = tid >> 6, lane = tid & 63;
  const int l15 = lane & 15, g = lane >> 4;
  __shared__ int toks[64];
  if (tid < 64)
    toks[tid] = (t == 0) ? tt[tid * TLEN]
                         : (int)(~(unsigned)(amax[tid] & 0xffffffffull));
  __syncthreads();
  const int ct = cb * 4 + w;
  const unsigned short* Bp = wihp + (size_t)ct * 32768;
  const int lo = lane * 8;
  f32x4 acc[4] = {};
#pragma unroll
  for (int k0l = 0; k0l < 8; k0l++) {
    const int k0 = ks * 8 + k0l;
    bf16x8 bh = *(const bf16x8*)(Bp + k0 * 1024 + lo);
    bf16x8 bl = *(const bf16x8*)(Bp + k0 * 1024 + 512 + lo);
#pragma unroll
    for (int m = 0; m < 4; m++) {
      const float* ep = emb + (size_t)toks[m * 16 + l15] * HID + k0 * 32 + g * 8;
      float4 f0 = *(const float4*)ep;
      float4 f1 = *(const float4*)(ep + 4);
      bf16x8 ah, al;
      split8(f0, f1, ah, al);
      acc[m] = __builtin_amdgcn_mfma_f32_16x16x32_bf16(ah, bh, acc[m], 0, 0, 0);
      acc[m] = __builtin_amdgcn_mfma_f32_16x16x32_bf16(al, bh, acc[m], 0, 0, 0);
      acc[m] = __builtin_amdgcn_mfma_f32_16x16x32_bf16(ah, bl, acc[m], 0, 0, 0);
    }
  }
  const int gcol = ct * 16 + l15;
  float* C = gib + (size_t)ks * 64 * 3072;
#pragma unroll
  for (int m = 0; m < 4; m++)
#pragma unroll
    for (int q = 0; q < 4; q++)
      C[(size_t)(m * 16 + g * 4 + q) * 3072 + gcol] = acc[m][q];
}

// ---------------- combine: GRU nonlinearity + h update + packed split + amax reset ----------------
__global__ __launch_bounds__(256) void k_combine(
    const float* __restrict__ gib, const float* __restrict__ ghb,
    const float* __restrict__ b_ih, const float* __restrict__ b_hh,
    float* __restrict__ h32, unsigned short* __restrict__ hfA,
    unsigned long long* __restrict__ amax) {
  const int idx = blockIdx.x * 256 + threadIdx.x;   // 64 x 1024
  const int r = idx >> 10, j = idx & 1023;
  float ir = b_ih[j], iz = b_ih[1024 + j], inn = b_ih[2048 + j];
#pragma unroll
  for (int s = 0; s < 4; s++) {
    const float* gs = gib + ((size_t)s * 64 + r) * 3072;
    ir += gs[j]; iz += gs[1024 + j]; inn += gs[2048 + j];
  }
  const float* gh = ghb + (size_t)r * 3072;
  float hr = b_hh[j] + gh[j];
  float hz = b_hh[1024 + j] + gh[1024 + j];
  float hn = b_hh[2048 + j] + gh[2048 + j];
  float rg = 1.f / (1.f + expf(-(ir + hr)));
  float zg = 1.f / (1.f + expf(-(iz + hz)));
  float nn = tanhf(inn + rg * hn);
  float hp = h32[idx];
  float h = (1.f - zg) * nn + zg * hp;
  h32[idx] = h;
  unsigned short hi_, lo_;
  split2(h, hi_, lo_);
  const int m = r >> 4, l15 = r & 15;
  const int k0 = j >> 5, s2 = (j >> 3) & 3, e = j & 7;
  const int lane = (s2 << 4) | l15;
  unsigned short* b = hfA + ((size_t)(m * 32 + k0) * 2) * 512 + lane * 8 + e;
  b[0] = hi_;
  b[512] = lo_;
  if (blockIdx.x == 0 && threadIdx.x < 64) amax[threadIdx.x] = 0ull;
}

// ---------------- gh for t=0 (standalone) ----------------
__global__ __launch_bounds__(256) void k_gh0(
    const unsigned short* __restrict__ whhp, const unsigned short* __restrict__ hfA,
    float* __restrict__ ghb) {
  const int tid = threadIdx.x;
  const int w = tid >> 6, lane = tid & 63;
  const int l15 = lane & 15, g = lane >> 4;
  f32x4 acc[4] = {};
  const int ct = blockIdx.x * 4 + w;
  gemm16_fullK(whhp + (size_t)ct * 32768, hfA, lane, acc);
  const int gcol = ct * 16 + l15;
#pragma unroll
  for (int m = 0; m < 4; m++)
#pragma unroll
    for (int q = 0; q < 4; q++)
      ghb[(size_t)(m * 16 + g * 4 + q) * 3072 + gcol] = acc[m][q];
}

// ======================= fp32 fallback path (round-1, known-good) =======================
#define O_FC_NCB 250
#define O_X2T_OFF  0
#define O_GBUF_OFF (2048*64)
#define O_PV_OFF   (O_GBUF_OFF + 8*64*4096)
#define O_PI_OFF   (O_PV_OFF + 64*O_FC_NCB)

__global__ __launch_bounds__(256) void o_prep(
    const float* __restrict__ enc, const int* __restrict__ tt,
    const float* __restrict__ emb, float* __restrict__ X2T,
    const float* __restrict__ pv, const int* __restrict__ pi, int t) {
  const int r = blockIdx.x;
  const int tid = threadIdx.x;
  __shared__ int s_tok;
  __shared__ float red_v[256];
  __shared__ int red_i[256];
  if (t == 0) {
    if (tid == 0) s_tok = tt[r * TLEN];
  } else {
    float v = -INFINITY; int idx = 0x7fffffff;
    if (tid < O_FC_NCB) { v = pv[r * O_FC_NCB + tid]; idx = pi[r * O_FC_NCB + tid]; }
    red_v[tid] = v; red_i[tid] = idx;
    __syncthreads();
    for (int s = 128; s > 0; s >>= 1) {
      if (tid < s) {
        float v2 = red_v[tid + s]; int i2 = red_i[tid + s];
        if (v2 > red_v[tid] || (v2 == red_v[tid] && i2 < red_i[tid])) {
          red_v[tid] = v2; red_i[tid] = i2;
        }
      }
      __syncthreads();
    }
    if (tid == 0) s_tok = red_i[0];
  }
  __syncthreads();
  const int tok = s_tok;
  for (int k = tid; k < HID; k += 256)
    X2T[(size_t)k * 64 + r] = emb[(size_t)tok * HID + k];
  if (t == 0) {
    for (int k = tid; k < HID; k += 256)
      X2T[(size_t)(HID + k) * 64 + r] = enc[r * HID + k];
  }
}

__global__ __launch_bounds__(256) void o_gates(
    const float* __restrict__ w_ih, const float* __restrict__ w_hh,
    const float* __restrict__ X2T, float* __restrict__ gbuf) {
  const int cb = blockIdx.x & 31;
  const int s  = blockIdx.x >> 5;
  const int g  = cb >> 3;
  if (g == 2 && s >= 4) return;
  if (g == 3 && s < 4) return;
  const int tid  = threadIdx.x;
  const int w    = __builtin_amdgcn_readfirstlane(tid >> 6);
  const int lane = tid & 63;
  const int r0   = (w >> 1) * 32;
  const int cc   = cb * 128 + (w & 1) * 64 + lane;
  const int j    = cc & 1023;
  const float* Bmat; int kk0;
  if (s < 4) { Bmat = w_ih; kk0 = s * 256; }
  else       { Bmat = w_hh; kk0 = (s - 4) * 256; }
  int brow;
  if (g == 0) brow = j;
  else if (g == 1) brow = 1024 + j;
  else brow = 2048 + j;
  const float* Bp = Bmat + (size_t)brow * HID + kk0;
  const float* Ap = X2T + (size_t)(s * 256) * 64 + r0;
  float acc[32];
#pragma unroll
  for (int i = 0; i < 32; i++) acc[i] = 0.f;
  for (int k = 0; k < 256; k += 4) {
    float4 b = *(const float4*)(Bp + k);
#pragma unroll
    for (int kk = 0; kk < 4; kk++) {
      const float bk = (&b.x)[kk];
      const float* a = Ap + (size_t)(k + kk) * 64;
#pragma unroll
      for (int i = 0; i < 32; i++) acc[i] = fmaf(a[i], bk, acc[i]);
    }
  }
  float* C = gbuf + (size_t)s * (64 * 4096) + cc;
#pragma unroll
  for (int i = 0; i < 32; i++) C[(size_t)(r0 + i) * 4096] = acc[i];
}

__global__ __launch_bounds__(256) void o_combine(
    const float* __restrict__ b_ih, const float* __restrict__ b_hh,
    const float* __restrict__ gbuf, float* __restrict__ X2T) {
  const int idx = blockIdx.x * 256 + threadIdx.x;
  const int r = idx >> 10;
  const int j = idx & 1023;
  const size_t SS = (size_t)64 * 4096;
  float sr  = b_ih[j] + b_hh[j];
  float sz  = b_ih[1024 + j] + b_hh[1024 + j];
  float inn = b_ih[2048 + j];
  float hn  = b_hh[2048 + j];
#pragma unroll
  for (int s = 0; s < 8; s++) {
    const float* gs = gbuf + s * SS + (size_t)r * 4096;
    sr += gs[j];
    sz += gs[1024 + j];
    if (s < 4) inn += gs[2048 + j]; else hn += gs[3072 + j];
  }
  float rg = 1.f / (1.f + expf(-sr));
  float zg = 1.f / (1.f + expf(-sz));
  float n  = tanhf(inn + rg * hn);
  float hp = X2T[(size_t)(1024 + j) * 64 + r];
  float h  = (1.f - zg) * n + zg * hp;
  X2T[(size_t)(1024 + j) * 64 + r] = h;
}

__global__ __launch_bounds__(256) void o_fc(
    const float* __restrict__ fc_w, const float* __restrict__ fc_b,
    const float* __restrict__ hT, float* __restrict__ out,
    float* __restrict__ pv, int* __restrict__ pi, int t) {
  const int tid  = threadIdx.x;
  const int w    = __builtin_amdgcn_readfirstlane(tid >> 6);
  const int lane = tid & 63;
  const int r0   = (w >> 1) * 32;
  const int col  = blockIdx.x * 128 + (w & 1) * 64 + lane;
  const float* Bp = fc_w + (size_t)col * HID;
  float acc[32];
#pragma unroll
  for (int i = 0; i < 32; i++) acc[i] = 0.f;
  for (int k = 0; k < HID; k += 4) {
    float4 b = *(const float4*)(Bp + k);
#pragma unroll
    for (int kk = 0; kk < 4; kk++) {
      const float bk = (&b.x)[kk];
      const float* a = hT + (size_t)(k + kk) * 64 + r0;
#pragma unroll
      for (int i = 0; i < 32; i++) acc[i] = fmaf(a[i], bk, acc[i]);
    }
  }
  const float bias = fc_b[col];
#pragma unroll
  for (int i = 0; i < 32; i++) {
    float v = acc[i] + bias;
    acc[i] = v;
    out[((size_t)(r0 + i) * TLEN + t) * VOCAB + col] = v;
  }
  __shared__ float sv[2][64];
  __shared__ int   si[2][64];
#pragma unroll 4
  for (int i = 0; i < 32; i++) {
    float v = acc[i]; int idx = col;
#pragma unroll
    for (int d = 32; d > 0; d >>= 1) {
      float v2 = __shfl_xor(v, d);
      int i2   = __shfl_xor(idx, d);
      if (v2 > v || (v2 == v && i2 < idx)) { v = v2; idx = i2; }
    }
    if (lane == 0) { sv[w & 1][r0 + i] = v; si[w & 1][r0 + i] = idx; }
  }
  __syncthreads();
  if (tid < 64) {
    float v = sv[0][tid]; int idx = si[0][tid];
    float v2 = sv[1][tid]; int i2 = si[1][tid];
    if (v2 > v || (v2 == v && i2 < idx)) { v = v2; idx = i2; }
    pv[tid * O_FC_NCB + blockIdx.x] = v;
    pi[tid * O_FC_NCB + blockIdx.x] = idx;
  }
}

// =======================================================================
extern "C" void kernel_launch(void* const* d_in, const int* in_sizes, int n_in,
                              void* d_out, int out_size, void* d_ws, size_t ws_size,
                              hipStream_t stream) {
  const float* enc  = (const float*)d_in[0];
  const int*   tt   = (const int*)d_in[1];
  const float* emb  = (const float*)d_in[2];
  const float* w_ih = (const float*)d_in[3];
  const float* w_hh = (const float*)d_in[4];
  const float* b_ih = (const float*)d_in[5];
  const float* b_hh = (const float*)d_in[6];
  const float* fc_w = (const float*)d_in[7];
  const float* fc_b = (const float*)d_in[8];
  float* out = (float*)d_out;

  if (ws_size >= WS_NEED) {
    char* ws = (char*)d_ws;
    unsigned short* fcwp = (unsigned short*)(ws + OFF_FCWP);
    unsigned short* wihp = (unsigned short*)(ws + OFF_WIHP);
    unsigned short* whhp = (unsigned short*)(ws + OFF_WHHP);
    unsigned short* hfA  = (unsigned short*)(ws + OFF_HFA);
    float* h32 = (float*)(ws + OFF_H32);
    float* gib = (float*)(ws + OFF_GIB);
    float* ghb = (float*)(ws + OFF_GHB);
    unsigned long long* amax = (unsigned long long*)(ws + OFF_AMAX);

    k_pack<<<(FC_TILES * 2048) / 256, 256, 0, stream>>>(fc_w, fcwp, FC_TILES);
    k_pack<<<(G_TILES * 2048) / 256, 256, 0, stream>>>(w_ih, wihp, G_TILES);
    k_pack<<<(G_TILES * 2048) / 256, 256, 0, stream>>>(w_hh, whhp, G_TILES);
    k_init<<<64, 256, 0, stream>>>(enc, h32, hfA);
    k_gi<<<192, 256, 0, stream>>>(emb, wihp, tt, amax, gib, 0);
    k_gh0<<<48, 256, 0, stream>>>(whhp, hfA, ghb);

    for (int t = 0; t < TLEN; t++) {
      k_combine<<<256, 256, 0, stream>>>(gib, ghb, b_ih, b_hh, h32, hfA, amax);
      k_fc<<<(t < TLEN - 1) ? 548 : 500, 256, 0, stream>>>(fcwp, whhp, hfA, fc_b,
                                                           out, ghb, amax, t);
      if (t < TLEN - 1)
        k_gi<<<192, 256, 0, stream>>>(emb, wihp, tt, amax, gib, t + 1);
    }
  } else {
    float* ws = (float*)d_ws;
    float* X2T  = ws + O_X2T_OFF;
    float* gbuf = ws + O_GBUF_OFF;
    float* pv   = ws + O_PV_OFF;
    int*   pi   = (int*)(ws + O_PI_OFF);
    for (int t = 0; t < TLEN; t++) {
      o_prep<<<64, 256, 0, stream>>>(enc, tt, emb, X2T, pv, pi, t);
      o_gates<<<256, 256, 0, stream>>>(w_ih, w_hh, X2T, gbuf);
      o_combine<<<256, 256, 0, stream>>>(b_ih, b_hh, gbuf, X2T);
      o_fc<<<O_FC_NCB, 256, 0, stream>>>(fc_w, fc_b, X2T + (size_t)HID * 64, out, pv, pi, t);
    }
  }
}